// Round 13
// baseline (107.946 us; speedup 1.0000x reference)
//
#include <hip/hip_runtime.h>

// ---------------------------------------------------------------------------
// LModel15: edge sampling + bilinear similarity loss (MI355X / gfx950)
// Outputs: [similarity_loss, normal_loss, normalization_loss] (3x fp32)
// R13: quad-565 texture (uint2 per pixel = 2x2 footprint: rows y,y+1 x cols
//      x,x+1 as 4xRGB565) -> ONE 8B load per image per sample (2 lookups,
//      was 4). Repack reads rows y and y+1 with plain (cached) loads so the
//      adjacent-row re-read hits L2/L3. edge_kernel merged into the repack
//      launch (blockIdx < nA => edge work). 4 launches total.
// ---------------------------------------------------------------------------

constexpr int NVS   = 10;
constexpr int IMG_H = 2000;
constexpr int IMG_W = 3000;
constexpr int NPIX  = IMG_H * IMG_W;
constexpr int QROW  = IMG_W / 4;          // 750 quads per row (exact)
constexpr int SAMPLE_BLOCKS = 2048;
constexpr unsigned CHUNK = 512;           // samples per chunk (2 per thread)

typedef float    fx4 __attribute__((ext_vector_type(4)));
typedef unsigned ux4 __attribute__((ext_vector_type(4)));

struct Geom {
    float p0x, p0y, p0z;
    float p1x, p1y, p1z;
    float p2x, p2y, p2z;
    float p3x, p3y, p3z;
    float cdx, cdy, cdz;
    float cnx, cny, cnz;
    float cux, cuy, cuz;
    float len;
    int   nh;
};

__device__ __forceinline__ Geom compute_geom(const float* __restrict__ ep, int e) {
    Geom g;
    const float* p = ep + (size_t)e * 12;
    g.p0x = p[0];  g.p0y = p[1];  g.p0z = p[2];
    g.p1x = p[3];  g.p1y = p[4];  g.p1z = p[5];
    g.p2x = p[6];  g.p2y = p[7];  g.p2z = p[8];
    g.p3x = p[9];  g.p3y = p[10]; g.p3z = p[11];

    float dx = g.p1x - g.p0x, dy = g.p1y - g.p0y, dz = g.p1z - g.p0z;
    float ax = dx + 1e-6f, ay = dy + 1e-6f, az = dz + 1e-6f;
    g.len = sqrtf(ax * ax + ay * ay + az * az);
    g.cdx = dx / g.len; g.cdy = dy / g.len; g.cdz = dz / g.len;

    float ndx = g.p3x - g.p1x, ndy = g.p3y - g.p1y, ndz = g.p3z - g.p1z;
    float cnx = g.cdy * ndz - g.cdz * ndy;
    float cny = g.cdz * ndx - g.cdx * ndz;
    float cnz = g.cdx * ndy - g.cdy * ndx;
    float n1 = sqrtf(cnx * cnx + cny * cny + cnz * cnz) + 1e-8f;
    cnx /= n1; cny /= n1; cnz /= n1;
    if (cnz > 0.f) { cnx = -cnx; cny = -cny; cnz = -cnz; }
    g.cnx = cnx; g.cny = cny; g.cnz = cnz;

    float cux = cny * g.cdz - cnz * g.cdy;
    float cuy = cnz * g.cdx - cnx * g.cdz;
    float cuz = cnx * g.cdy - cny * g.cdx;
    float n2 = sqrtf(cux * cux + cuy * cuy + cuz * cuz) + 1e-8f;
    g.cux = cux / n2; g.cuy = cuy / n2; g.cuz = cuz / n2;

    int nh = (int)floorf(g.len / 0.05f);
    g.nh = nh < 2 ? 2 : (nh > 1000 ? 1000 : nh);
    return g;
}

__device__ __forceinline__ double block_reduce_d(double v) {
    __shared__ double sh[256];
    int tid = threadIdx.x;
    sh[tid] = v;
    __syncthreads();
    for (int s = 128; s > 0; s >>= 1) {
        if (tid < s) sh[tid] += sh[tid + s];
        __syncthreads();
    }
    double r = sh[0];
    __syncthreads();
    return r;
}

// ---------------------------------------------------------------------------
// pack helper: RGB565
// ---------------------------------------------------------------------------
__device__ __forceinline__ unsigned p565(float r, float g, float b) {
    unsigned ri = (unsigned)__float2int_rn(r * 31.0f) & 31u;
    unsigned gi = (unsigned)__float2int_rn(g * 63.0f) & 63u;
    unsigned bi = (unsigned)__float2int_rn(b * 31.0f) & 31u;
    return ri | (gi << 5) | (bi << 11);
}

// ---------------------------------------------------------------------------
// union kernel: blocks [0, nA) do per-edge losses + geometry; blocks >= nA
// repack CHW fp32 -> quad-565 (uint2/pixel: {rowY dual, rowY+1 dual}).
// ---------------------------------------------------------------------------
__global__ __launch_bounds__(256) void edge_repack_kernel(
        const float* __restrict__ ep, int E, int nA,
        double* __restrict__ normal_part,
        double* __restrict__ norz_part,
        fx4* __restrict__ geom_out,
        int* __restrict__ nh_out,
        const float* __restrict__ img1, const float* __restrict__ img2,
        uint2* __restrict__ o1, uint2* __restrict__ o2) {
    if ((int)blockIdx.x < nA) {
        // ---- edge part ----
        int e = blockIdx.x * blockDim.x + threadIdx.x;
        double t1 = 0.0, t2 = 0.0;
        if (e < E) {
            Geom g = compute_geom(ep, e);
            float pdx = g.p0x - g.p2x, pdy = g.p0y - g.p2y, pdz = g.p0z - g.p2z;
            float pnx = pdy * g.cdz - pdz * g.cdy;
            float pny = pdz * g.cdx - pdx * g.cdz;
            float pnz = pdx * g.cdy - pdy * g.cdx;
            float n = sqrtf(pnx * pnx + pny * pny + pnz * pnz) + 1e-8f;
            pnx /= n; pny /= n; pnz /= n;
            float dotn = g.cnx * pnx + g.cny * pny + g.cnz * pnz;
            t1 = (double)(1.0f - dotn);

            float ox = g.p0y * g.p1z - g.p0z * g.p1y;
            float oy = g.p0z * g.p1x - g.p0x * g.p1z;
            float oz = g.p0x * g.p1y - g.p0y * g.p1x;
            float no = sqrtf(ox * ox + oy * oy + oz * oz) + 1e-8f;
            ox /= no; oy /= no; oz /= no;
            float snp = fminf(fabsf(g.cux * ox + g.cuy * oy + g.cuz * oz), 0.5f);
            t2 = (double)(1.0f - snp / 0.5f);

            fx4 f0 = {g.cdx, g.cdy, g.cdz, g.len};
            fx4 f1 = {g.cux, g.cuy, g.cuz, 1.0f / (float)(g.nh - 1)};
            fx4 f2 = {g.p0x, g.p0y, g.p0z, 0.f};
            geom_out[e * 3 + 0] = f0;
            geom_out[e * 3 + 1] = f1;
            geom_out[e * 3 + 2] = f2;
            nh_out[e] = g.nh;
        }
        double s1 = block_reduce_d(t1);
        double s2 = block_reduce_d(t2);
        if (threadIdx.x == 0) {
            normal_part[blockIdx.x] = s1;
            norz_part[blockIdx.x]   = s2;
        }
        return;
    }

    // ---- repack part (quad-565) ----
    const int nq = NPIX / 4;
    int idx = ((int)blockIdx.x - nA) * 256 + (int)threadIdx.x;
    bool act = idx < 2 * nq;

    const float* img = img1;
    uint2* out = o1;
    int q = 0, q1 = 0, qrow = 0;
    unsigned h0 = 0, h1 = 0, h2 = 0, h3 = 0;
    unsigned g0 = 0, g1 = 0, g2 = 0, g3 = 0;

    if (act) {
        if (idx < nq) { img = img1; out = o1; q = idx; }
        else          { img = img2; out = o2; q = idx - nq; }
        int y = q / QROW;
        qrow = q - y * QROW;
        int y1 = y + 1 < IMG_H ? y + 1 : IMG_H - 1;
        q1 = y1 * QROW + qrow;

        // plain (cached) loads: row y1 quad is re-read by the row-y1 thread,
        // L2/L3 absorbs the second pass. No nontemporal here (R11 lesson).
        fx4 r0 = reinterpret_cast<const fx4*>(img)[q];
        fx4 c0 = reinterpret_cast<const fx4*>(img + NPIX)[q];
        fx4 b0 = reinterpret_cast<const fx4*>(img + 2 * (size_t)NPIX)[q];
        fx4 r1 = reinterpret_cast<const fx4*>(img)[q1];
        fx4 c1 = reinterpret_cast<const fx4*>(img + NPIX)[q1];
        fx4 b1 = reinterpret_cast<const fx4*>(img + 2 * (size_t)NPIX)[q1];

        h0 = p565(r0.x, c0.x, b0.x); h1 = p565(r0.y, c0.y, b0.y);
        h2 = p565(r0.z, c0.z, b0.z); h3 = p565(r0.w, c0.w, b0.w);
        g0 = p565(r1.x, c1.x, b1.x); g1 = p565(r1.y, c1.y, b1.y);
        g2 = p565(r1.z, c1.z, b1.z); g3 = p565(r1.w, c1.w, b1.w);
    }

    unsigned h4s = __shfl_down(h0, 1, 64);   // lane+1's first pixel, row y
    unsigned g4s = __shfl_down(g0, 1, 64);   // lane+1's first pixel, row y1

    if (act) {
        unsigned h4, g4;
        if (qrow == QROW - 1) {
            h4 = h3; g4 = g3;                 // clamp: last col pairs with itself
        } else if ((threadIdx.x & 63) == 63) {
            int nx  = q  * 4 + 4;             // rare wave-boundary fallback
            int nx1 = q1 * 4 + 4;
            h4 = p565(img[nx],  img[NPIX + nx],  img[2 * (size_t)NPIX + nx]);
            g4 = p565(img[nx1], img[NPIX + nx1], img[2 * (size_t)NPIX + nx1]);
        } else {
            h4 = h4s; g4 = g4s;
        }
        // entry for pixel x=q*4+k: uint2{ rowY: hk|hk+1<<16, rowY1: gk|gk+1<<16 }
        ux4 lo, hi;
        lo.x = h0 | (h1 << 16); lo.y = g0 | (g1 << 16);
        lo.z = h1 | (h2 << 16); lo.w = g1 | (g2 << 16);
        hi.x = h2 | (h3 << 16); hi.y = g2 | (g3 << 16);
        hi.z = h3 | (h4 << 16); hi.w = g3 | (g4 << 16);
        reinterpret_cast<ux4*>(out)[q * 2]     = lo;
        reinterpret_cast<ux4*>(out)[q * 2 + 1] = hi;
    }
}

// ---------------------------------------------------------------------------
// prep: thread-coarsened prefix scan of nh*10 -> cum, plus (thread 0)
// transform = K2h @ E2 @ inv(E1). One launch.
// ---------------------------------------------------------------------------
__global__ __launch_bounds__(256) void prep_kernel(
        const int* __restrict__ nh, int E, unsigned* __restrict__ cum,
        const float* __restrict__ K2, const float* __restrict__ E1,
        const float* __restrict__ E2, float* __restrict__ tf) {
    __shared__ unsigned ssum[256];
    int tid = threadIdx.x;
    int K = (E + 255) / 256;
    int base = tid * K;

    unsigned s = 0;
    for (int k = 0; k < K; ++k) {
        int idx = base + k;
        if (idx < E) s += (unsigned)(nh[idx] * NVS);
    }
    ssum[tid] = s;
    __syncthreads();
    for (int off = 1; off < 256; off <<= 1) {
        unsigned add = (tid >= off) ? ssum[tid - off] : 0u;
        __syncthreads();
        ssum[tid] += add;
        __syncthreads();
    }
    unsigned run = ssum[tid] - s;
    for (int k = 0; k < K; ++k) {
        int idx = base + k;
        if (idx < E) {
            run += (unsigned)(nh[idx] * NVS);
            cum[idx + 1] = run;
        }
    }
    if (tid == 0) {
        cum[0] = 0;

        double a[4][8];
        for (int r = 0; r < 4; ++r)
            for (int c = 0; c < 4; ++c) {
                a[r][c] = (double)E1[r * 4 + c];
                a[r][4 + c] = (r == c) ? 1.0 : 0.0;
            }
        for (int col = 0; col < 4; ++col) {
            int piv = col; double best = fabs(a[col][col]);
            for (int r = col + 1; r < 4; ++r) {
                double t = fabs(a[r][col]);
                if (t > best) { best = t; piv = r; }
            }
            if (piv != col)
                for (int c = 0; c < 8; ++c) { double t = a[col][c]; a[col][c] = a[piv][c]; a[piv][c] = t; }
            double d = a[col][col];
            for (int c = 0; c < 8; ++c) a[col][c] /= d;
            for (int r = 0; r < 4; ++r) {
                if (r == col) continue;
                double f = a[r][col];
                for (int c = 0; c < 8; ++c) a[r][c] -= f * a[col][c];
            }
        }
        double inv1[4][4];
        for (int r = 0; r < 4; ++r)
            for (int c = 0; c < 4; ++c) inv1[r][c] = a[r][4 + c];

        double k2h[4][4];
        for (int r = 0; r < 4; ++r)
            for (int c = 0; c < 4; ++c) k2h[r][c] = (r == c) ? 1.0 : 0.0;
        for (int r = 0; r < 3; ++r)
            for (int c = 0; c < 3; ++c) k2h[r][c] = (double)K2[r * 3 + c];

        double m1[4][4];
        for (int r = 0; r < 4; ++r)
            for (int c = 0; c < 4; ++c) {
                double sm = 0.0;
                for (int k = 0; k < 4; ++k) sm += (double)E2[r * 4 + k] * inv1[k][c];
                m1[r][c] = sm;
            }
        for (int r = 0; r < 4; ++r)
            for (int c = 0; c < 4; ++c) {
                double sm = 0.0;
                for (int k = 0; k < 4; ++k) sm += k2h[r][k] * m1[k][c];
                tf[r * 4 + c] = (float)sm;
            }
    }
}

// ---------------------------------------------------------------------------
// bilinear sample of quad-565 texture: ONE 8B gather per image.
// Channels returned in [0,31]/[0,63]/[0,31] scale.
// ---------------------------------------------------------------------------
__device__ __forceinline__ void sample_q565(const uint2* __restrict__ img,
                                            float u, float v,
                                            float& r, float& g, float& b) {
    float x = u * (float)IMG_W - 0.5f;
    float y = v * (float)IMG_H - 0.5f;
    float x0 = floorf(x), y0 = floorf(y);
    float wx = x - x0, wy = y - y0;
    int x0i = (int)x0; x0i = x0i < 0 ? 0 : (x0i > IMG_W - 1 ? IMG_W - 1 : x0i);
    int y0i = (int)y0; y0i = y0i < 0 ? 0 : (y0i > IMG_H - 1 ? IMG_H - 1 : y0i);

    uint2 T = img[(size_t)y0i * IMG_W + x0i];
    unsigned t0 = T.x;   // row y0: (x0, x1)
    unsigned t1 = T.y;   // row y1: (x0, x1)

    float w00 = (1.f - wx) * (1.f - wy);
    float w10 = wx * (1.f - wy);
    float w01 = (1.f - wx) * wy;
    float w11 = wx * wy;

    r = w00 * (float)(t0 & 31u)         + w10 * (float)((t0 >> 16) & 31u)
      + w01 * (float)(t1 & 31u)         + w11 * (float)((t1 >> 16) & 31u);
    g = w00 * (float)((t0 >> 5) & 63u)  + w10 * (float)((t0 >> 21) & 63u)
      + w01 * (float)((t1 >> 5) & 63u)  + w11 * (float)((t1 >> 21) & 63u);
    b = w00 * (float)((t0 >> 11) & 31u) + w10 * (float)((t0 >> 27) & 31u)
      + w01 * (float)((t1 >> 11) & 31u) + w11 * (float)((t1 >> 27) & 31u);
}

// fp32 CHW fallback
__device__ __forceinline__ void bilinear3(const float* __restrict__ img,
                                          float u, float v,
                                          float& r, float& g, float& b) {
    float x = u * (float)IMG_W - 0.5f;
    float y = v * (float)IMG_H - 0.5f;
    float x0 = floorf(x), y0 = floorf(y);
    float wx = x - x0, wy = y - y0;
    int x0i = (int)x0; x0i = x0i < 0 ? 0 : (x0i > IMG_W - 1 ? IMG_W - 1 : x0i);
    int x1i = x0i + 1; x1i = x1i > IMG_W - 1 ? IMG_W - 1 : x1i;
    int y0i = (int)y0; y0i = y0i < 0 ? 0 : (y0i > IMG_H - 1 ? IMG_H - 1 : y0i);
    int y1i = y0i + 1; y1i = y1i > IMG_H - 1 ? IMG_H - 1 : y1i;
    float w00 = (1.f - wx) * (1.f - wy);
    float w10 = wx * (1.f - wy);
    float w01 = (1.f - wx) * wy;
    float w11 = wx * wy;
    float out[3];
#pragma unroll
    for (int c = 0; c < 3; ++c) {
        const float* p = img + (size_t)c * NPIX;
        float v00 = p[(size_t)y0i * IMG_W + x0i];
        float v10 = p[(size_t)y0i * IMG_W + x1i];
        float v01 = p[(size_t)y1i * IMG_W + x0i];
        float v11 = p[(size_t)y1i * IMG_W + x1i];
        out[c] = v00 * w00 + v10 * w10 + v01 * w01 + v11 * w11;
    }
    r = out[0]; g = out[1]; b = out[2];
}

__device__ __forceinline__ int find_edge(const unsigned* __restrict__ cum,
                                         int E, unsigned s) {
    int lo = 0, hi = E - 1;
    while (lo < hi) {
        int mid = (lo + hi + 1) >> 1;
        if (cum[mid] <= s) lo = mid; else hi = mid - 1;
    }
    return lo;
}

// ---------------------------------------------------------------------------
// flattened sampling (R9 structure): grid-stride over 512-sample chunks,
// 2 samples/thread, register accumulation, ONE block reduce at the end.
// ---------------------------------------------------------------------------
template <bool PACKED>
__global__ __launch_bounds__(256) void sample_kernel_t(
        const fx4* __restrict__ geom,
        const unsigned* __restrict__ cum, int E,
        const void* __restrict__ vimg1,
        const void* __restrict__ vimg2,
        const float* __restrict__ K1,
        const float* __restrict__ tf,
        double* __restrict__ sim_part) {
    __shared__ int sh_ea[2], sh_eb[2];
    int tid = threadIdx.x;

    unsigned NS = cum[E];
    unsigned nch = (NS + CHUNK - 1u) / CHUNK;

    float k00 = K1[0], k01 = K1[1], k02 = K1[2];
    float k10 = K1[3], k11 = K1[4], k12 = K1[5];
    float k20 = K1[6], k21 = K1[7], k22 = K1[8];
    float t00 = tf[0],  t01 = tf[1],  t02 = tf[2],  t03 = tf[3];
    float t10 = tf[4],  t11 = tf[5],  t12 = tf[6],  t13 = tf[7];
    float t20 = tf[8],  t21 = tf[9],  t22 = tf[10], t23 = tf[11];

    const uint2* img1 = (const uint2*)vimg1;
    const uint2* img2 = (const uint2*)vimg2;
    const float* fimg1 = (const float*)vimg1;
    const float* fimg2 = (const float*)vimg2;

    const float INV31 = 1.0f / 31.0f;
    const float INV63 = 1.0f / 63.0f;

    double lsum = 0.0;
    int it = 0;

    auto sample_one = [&](unsigned s, int e) {
        while (e + 1 < E && cum[e + 1] <= s) ++e;
        unsigned q = s - cum[e];
        int i = (int)(q / (unsigned)NVS);
        int j = (int)(q - (unsigned)(i * NVS));

        fx4 f0 = geom[e * 3 + 0];
        fx4 f1 = geom[e * 3 + 1];
        fx4 f2 = geom[e * 3 + 2];

        float dxv = ((float)i * f1.w) * f0.w;
        float dyv = ((float)j / 9.0f) * 0.5f;

        float px = f0.x * dxv + f1.x * dyv + f2.x;
        float py = f0.y * dxv + f1.y * dyv + f2.y;
        float pz = f0.z * dxv + f1.z * dyv + f2.z;

        float w1 = k20 * px + k21 * py + k22 * pz;
        float u1 = (k00 * px + k01 * py + k02 * pz) / w1;
        float v1 = (k10 * px + k11 * py + k12 * pz) / w1;
        u1 = fminf(fmaxf(u1, 0.f), 0.999999f);
        v1 = fminf(fmaxf(v1, 0.f), 0.999999f);

        float w2 = t20 * px + t21 * py + t22 * pz + t23;
        float u2 = (t00 * px + t01 * py + t02 * pz + t03) / w2;
        float v2 = (t10 * px + t11 * py + t12 * pz + t13) / w2;
        u2 = fminf(fmaxf(u2, 0.f), 0.999999f);
        v2 = fminf(fmaxf(v2, 0.f), 0.999999f);

        if constexpr (PACKED) {
            float ar, ag, ab, br, bg, bb;
            sample_q565(img1, u1, v1, ar, ag, ab);
            sample_q565(img2, u2, v2, br, bg, bb);
            float dr = (ar - br) * INV31;
            float dg = (ag - bg) * INV63;
            float db = (ab - bb) * INV31;
            lsum += (double)(dr * dr) + (double)(dg * dg) + (double)(db * db);
        } else {
            float ar, ag, ab, br, bg, bb;
            bilinear3(fimg1, u1, v1, ar, ag, ab);
            bilinear3(fimg2, u2, v2, br, bg, bb);
            float dr = ar - br, dg = ag - bg, db = ab - bb;
            lsum += (double)(dr * dr) + (double)(dg * dg) + (double)(db * db);
        }
    };

    for (unsigned chunk = blockIdx.x; chunk < nch; chunk += gridDim.x, ++it) {
        unsigned sbase = chunk * CHUNK;
        int par = it & 1;
        if (tid == 0) {
            sh_ea[par] = find_edge(cum, E, sbase);
            unsigned smid = sbase + 256u;
            sh_eb[par] = find_edge(cum, E, smid < NS ? smid : NS - 1u);
        }
        __syncthreads();
        int ea = sh_ea[par];
        int eb = sh_eb[par];

        unsigned sA = sbase + (unsigned)tid;
        unsigned sB = sA + 256u;
        if (sA < NS) sample_one(sA, ea);
        if (sB < NS) sample_one(sB, eb);
    }

    double tot = block_reduce_d(lsum);
    if (tid == 0) sim_part[blockIdx.x] = tot;
}

// ---------------------------------------------------------------------------
// finalize
// ---------------------------------------------------------------------------
__global__ __launch_bounds__(256) void finalize_kernel(
        const double* __restrict__ sim_part, int n_sim,
        const unsigned* __restrict__ cum, int E,
        const double* __restrict__ normal_part,
        const double* __restrict__ norz_part, int n_a,
        float* __restrict__ out) {
    int tid = threadIdx.x;
    unsigned NS = cum[E];

    double s = 0.0;
    for (int i = tid; i < n_sim; i += 256) s += sim_part[i];
    double sim = block_reduce_d(s);

    s = 0.0;
    for (int i = tid; i < n_a; i += 256) s += normal_part[i];
    double nrm = block_reduce_d(s);

    s = 0.0;
    for (int i = tid; i < n_a; i += 256) s += norz_part[i];
    double nz = block_reduce_d(s);

    if (tid == 0) {
        double total = (double)NS * 3.0;
        out[0] = (float)(sim / total);
        out[1] = (float)((nrm / (double)E) * 0.5);
        out[2] = (float)(nz / (double)E);
    }
}

// ---------------------------------------------------------------------------
extern "C" void kernel_launch(void* const* d_in, const int* in_sizes, int n_in,
                              void* d_out, int out_size, void* d_ws, size_t ws_size,
                              hipStream_t stream) {
    const float* ep  = (const float*)d_in[0];
    const float* im1 = (const float*)d_in[1];
    const float* im2 = (const float*)d_in[2];
    const float* K1  = (const float*)d_in[3];
    const float* K2  = (const float*)d_in[4];
    const float* E1  = (const float*)d_in[5];
    const float* E2  = (const float*)d_in[6];
    float* out = (float*)d_out;

    int E  = in_sizes[0] / 12;
    int nA = (E + 255) / 256;

    size_t img_bytes = (size_t)NPIX * 8;   // quad-565, 8B/pixel

    char* ws = (char*)d_ws;
    size_t off = 0;
    auto alloc = [&](size_t bytes) {
        size_t o = off;
        off = (off + bytes + 255) & ~(size_t)255;
        return (void*)(ws + o);
    };

    fx4*      geom        = (fx4*)alloc((size_t)E * 48);
    int*      nh_arr      = (int*)alloc((size_t)E * 4);
    unsigned* cum         = (unsigned*)alloc((size_t)(E + 1) * 4);
    float*    tf          = (float*)alloc(64);
    double*   sim_part    = (double*)alloc((size_t)SAMPLE_BLOCKS * 8);
    double*   normal_part = (double*)alloc((size_t)nA * 8);
    double*   norz_part   = (double*)alloc((size_t)nA * 8);
    size_t tail_bytes = off;

    bool packed = ws_size >= tail_bytes + 2 * img_bytes + 512;
    uint2* p1 = nullptr;
    uint2* p2 = nullptr;
    if (packed) {
        p1 = (uint2*)alloc(img_bytes);
        p2 = (uint2*)alloc(img_bytes);
    }

    if (packed) {
        const int nq2 = 2 * (NPIX / 4);
        int nRep = (nq2 + 255) / 256;
        edge_repack_kernel<<<nA + nRep, 256, 0, stream>>>(
            ep, E, nA, normal_part, norz_part, geom, nh_arr, im1, im2, p1, p2);
        prep_kernel<<<1, 256, 0, stream>>>(nh_arr, E, cum, K2, E1, E2, tf);
        sample_kernel_t<true><<<SAMPLE_BLOCKS, 256, 0, stream>>>(
            geom, cum, E, (const void*)p1, (const void*)p2, K1, tf, sim_part);
    } else {
        edge_repack_kernel<<<nA, 256, 0, stream>>>(
            ep, E, nA, normal_part, norz_part, geom, nh_arr, im1, im2, nullptr, nullptr);
        prep_kernel<<<1, 256, 0, stream>>>(nh_arr, E, cum, K2, E1, E2, tf);
        sample_kernel_t<false><<<SAMPLE_BLOCKS, 256, 0, stream>>>(
            geom, cum, E, (const void*)im1, (const void*)im2, K1, tf, sim_part);
    }
    finalize_kernel<<<1, 256, 0, stream>>>(sim_part, SAMPLE_BLOCKS, cum, E,
                                           normal_part, norz_part, nA, out);
}